// Round 4
// baseline (1143.219 us; speedup 1.0000x reference)
//
#include <hip/hip_runtime.h>
#include <hip/hip_bf16.h>
#include <math.h>

#define NNODES 65536
#define NEDGES 1048576
#define NGRAPHS 64

typedef __attribute__((ext_vector_type(8))) short short8;
typedef __attribute__((ext_vector_type(4))) float f32x4;

// ---- order-preserving float<->uint encoding for atomicMax-based max ----
__device__ __forceinline__ unsigned encf(float f) {
    unsigned u = __float_as_uint(f);
    return (u & 0x80000000u) ? ~u : (u | 0x80000000u);
}
__device__ __forceinline__ float decf(unsigned u) {
    unsigned v = (u & 0x80000000u) ? (u & 0x7FFFFFFFu) : ~u;
    return __uint_as_float(v);
}
#define ENC_NEG_INF 0x007FFFFFu   // encf(-inf)

// RNE float -> bf16 bits (finite values only)
__device__ __forceinline__ unsigned bfbits(float f) {
    unsigned u = __float_as_uint(f);
    return (u + 0x7FFFu + ((u >> 16) & 1u)) >> 16;
}
__device__ __forceinline__ unsigned pk2(float a, float b) {
    return bfbits(a) | (bfbits(b) << 16);
}
__device__ __forceinline__ float bflo(unsigned p) { return __uint_as_float(p << 16); }
__device__ __forceinline__ float bfhi(unsigned p) { return __uint_as_float(p & 0xFFFF0000u); }

// async 16B/lane global->LDS (per-lane global addr; LDS dest = uniform base + lane*16)
#define GLDS16(g, l)                                                                     \
    __builtin_amdgcn_global_load_lds((const __attribute__((address_space(1))) unsigned*)(g), \
                                     (__attribute__((address_space(3))) unsigned*)(l), 16, 0, 0)

__device__ __forceinline__ void storeY(float* p, float v) { *p = v; }
__device__ __forceinline__ void storeY(unsigned short* p, float v) { *p = (unsigned short)bfbits(v); }

// ============================ CSR build ============================
__global__ void k_init(int* deg, int* cursor, unsigned* poolEnc) {
    int i = blockIdx.x * 256 + threadIdx.x;
    if (i < NNODES) { deg[i] = 0; cursor[i] = 0; }
    if (i < NGRAPHS * 256) poolEnc[i] = ENC_NEG_INF;
}

__global__ void k_count(const int* __restrict__ ei, int* deg) {
    int e = blockIdx.x * 256 + threadIdx.x;
    atomicAdd(&deg[ei[NEDGES + e]], 1);
}

__global__ void k_scan1(const int* __restrict__ deg, int* rowptr, int* bsum) {
    __shared__ int s[256];
    int t = threadIdx.x, b = blockIdx.x;
    int v = deg[b * 256 + t];
    s[t] = v;
    __syncthreads();
    for (int off = 1; off < 256; off <<= 1) {
        int x = (t >= off) ? s[t - off] : 0;
        __syncthreads();
        if (t >= off) s[t] += x;
        __syncthreads();
    }
    rowptr[b * 256 + t] = s[t] - v;       // local exclusive
    if (t == 255) bsum[b] = s[255];
}

__global__ void k_scan2(const int* __restrict__ bsum, int* boff) {
    __shared__ int s[256];
    int t = threadIdx.x;
    int v = bsum[t];
    s[t] = v;
    __syncthreads();
    for (int off = 1; off < 256; off <<= 1) {
        int x = (t >= off) ? s[t - off] : 0;
        __syncthreads();
        if (t >= off) s[t] += x;
        __syncthreads();
    }
    boff[t] = s[t] - v;                   // exclusive block offsets
}

__global__ void k_scan3(int* rowptr, const int* __restrict__ boff) {
    int i = blockIdx.x * 256 + threadIdx.x;
    rowptr[i] += boff[blockIdx.x];
    if (i == 0) rowptr[NNODES] = NEDGES;
}

__global__ void k_scatter(const int* __restrict__ ei, const int* __restrict__ rowptr,
                          int* cursor, int* csr_src, int* csr_dst) {
    int e = blockIdx.x * 256 + threadIdx.x;
    int s = ei[e], d = ei[NEDGES + e];
    int pos = rowptr[d] + atomicAdd(&cursor[d], 1);
    csr_src[pos] = s;
    csr_dst[pos] = d;
}

// ============== layer-1 U/V precompute (scalar, FIN=3 is trivial) ==============
template <int FIN, int H>
__global__ __launch_bounds__(256) void k_uv(const float* __restrict__ X,
                                            const float* __restrict__ W1,
                                            const float* __restrict__ B1,
                                            float* __restrict__ U,
                                            unsigned short* __restrict__ Vb) {
    constexpr int NPT = (16 * H) / 256;
    __shared__ float xs[16][FIN];
    int tid = threadIdx.x;
    int n0 = blockIdx.x * 16;
    for (int idx = tid; idx < 16 * FIN; idx += 256)
        xs[idx / FIN][idx % FIN] = X[(size_t)(n0 + idx / FIN) * FIN + (idx % FIN)];
    __syncthreads();
    int h = tid & (H - 1);
    int nb = (tid / H) * NPT;
    float u[NPT], v[NPT];
    float bb = B1[h];
#pragma unroll
    for (int n = 0; n < NPT; n++) { u[n] = bb; v[n] = 0.f; }
    for (int f = 0; f < FIN; f++) {
        float wt = W1[f * H + h];
        float wb = W1[(FIN + f) * H + h];
        float wd = wt - wb;
#pragma unroll
        for (int n = 0; n < NPT; n++) {
            float xv = xs[nb + n][f];
            u[n] += xv * wd;
            v[n] += xv * wb;
        }
    }
#pragma unroll
    for (int n = 0; n < NPT; n++) {
        U[(size_t)(n0 + nb + n) * H + h] = u[n];
        Vb[(size_t)(n0 + nb + n) * H + h] = (unsigned short)bfbits(v[n]);
    }
}

// ============== layers-2/3 U/V precompute via MFMA ==============
// [U | V] = X @ [Wd | Wb], Wd = W1_top - W1_bot, Wb = W1_bot. X is bf16.
// Block: CWAVES waves, 32 nodes per block. U written fp32 (+b1), V written bf16.
template <int K, int H, int CWAVES>
__global__ __launch_bounds__(CWAVES * 64, 4)
void k_uvm(const unsigned short* __restrict__ Xb,
           const float* __restrict__ W1,
           const float* __restrict__ B1,
           float* __restrict__ U,
           unsigned short* __restrict__ Vb) {
    constexpr int BLOCK = CWAVES * 64;
    constexpr int KP = K + 8;
    constexpr int CPW = (2 * H) / CWAVES;
    constexpr int NT = CPW / 16;
    constexpr int KS = K / 32;
    static_assert(BLOCK == 32 * (K / 8), "X-stage mapping");

    __shared__ unsigned short xs[32 * KP];

    int tid = threadIdx.x;
    int n0 = blockIdx.x * 32;
    int ln = tid & 15;
    int qd = (tid >> 4) & 3;
    int cw = tid >> 6;

    // stage X tile (32 x K bf16), padded stride
    {
        int r = tid / (K / 8);
        int ck = (tid % (K / 8)) * 8;
        uint4 w = *(const uint4*)&Xb[(size_t)(n0 + r) * K + ck];
        *(uint4*)&xs[r * KP + ck] = w;
    }

    // B fragments: cols [0,H) = Wd, [H,2H) = Wb
    short8 Bf[NT][KS];
#pragma unroll
    for (int nt = 0; nt < NT; nt++) {
        int col = cw * CPW + nt * 16 + ln;
#pragma unroll
        for (int ks = 0; ks < KS; ks++) {
            int kb = ks * 32 + qd * 8;
            short8 b;
#pragma unroll
            for (int j = 0; j < 8; j++) {
                int k = kb + j;
                float v;
                if (col < H) v = W1[(size_t)k * H + col] - W1[(size_t)(K + k) * H + col];
                else         v = W1[(size_t)(K + k) * H + (col - H)];
                b[j] = (short)bfbits(v);
            }
            Bf[nt][ks] = b;
        }
    }
    __syncthreads();

    f32x4 acc[2][NT];
#pragma unroll
    for (int mt = 0; mt < 2; mt++)
#pragma unroll
        for (int nt = 0; nt < NT; nt++)
            acc[mt][nt] = (f32x4){0.f, 0.f, 0.f, 0.f};

#pragma unroll
    for (int ks = 0; ks < KS; ks++) {
        int ko = ks * 32 + qd * 8;
        short8 a0 = *(const short8*)&xs[ln * KP + ko];
        short8 a1 = *(const short8*)&xs[(16 + ln) * KP + ko];
#pragma unroll
        for (int nt = 0; nt < NT; nt++) {
            acc[0][nt] = __builtin_amdgcn_mfma_f32_16x16x32_bf16(a0, Bf[nt][ks], acc[0][nt], 0, 0, 0);
            acc[1][nt] = __builtin_amdgcn_mfma_f32_16x16x32_bf16(a1, Bf[nt][ks], acc[1][nt], 0, 0, 0);
        }
    }

#pragma unroll
    for (int mt = 0; mt < 2; mt++) {
#pragma unroll
        for (int nt = 0; nt < NT; nt++) {
            int col = cw * CPW + nt * 16 + ln;
#pragma unroll
            for (int j = 0; j < 4; j++) {
                int node = n0 + mt * 16 + qd * 4 + j;
                float v = acc[mt][nt][j];
                if (col < H) U[(size_t)node * H + col] = v + B1[col];
                else         Vb[(size_t)node * H + (col - H)] = (unsigned short)bfbits(v);
            }
        }
    }
}

// ================= fused edge-GEMM (MFMA bf16) + segment-max =================
// Block owns 16 dst nodes + all their in-edges (CSR) -> no global atomics.
// Pipeline: while tile t runs MFMA+merge, tile t+1's V rows are DMA'd into
// ldsV via global_load_lds (per-lane gather addresses); the barrier's vmcnt
// drain lands after the MFMA phase, so gather latency leaves the critical path.
template <int H, int F, int RWAVES, int CWAVES, typename YT>
__global__ __launch_bounds__(RWAVES * CWAVES * 64, 4)
void k_agg(const float* __restrict__ U,
           const unsigned short* __restrict__ Vb,
           const float* __restrict__ W2,
           const float* __restrict__ B2,
           const int* __restrict__ rowptr,
           const int* __restrict__ csr_src,
           const int* __restrict__ csr_dst,
           YT* __restrict__ Y) {
    constexpr int BLOCK = RWAVES * CWAVES * 64;
    constexpr int NW = BLOCK / 64;          // waves per block
    constexpr int TR = 32 * RWAVES;         // edge rows per tile
    constexpr int HP = H + 8;               // padded hs row (bf16 units)
    constexpr int CPW = F / CWAVES;         // cols per wave
    constexpr int NT = CPW / 16;
    constexpr int KS = H / 32;
    constexpr int ACCSTR = F + 1;
    constexpr int LPR = H / 8;              // threads per hs row (8 elems each)
    constexpr int RPP = BLOCK / LPR;        // rows per construction pass
    constexpr int CPR = (H * 2) / 16;       // 16B chunks per V row
    constexpr int RPI = 64 / CPR;           // V rows per DMA instruction
    constexpr int RPW = TR / NW;            // V rows per wave
    constexpr int IPW = RPW / RPI;          // DMA instrs per wave
    static_assert(H % 32 == 0 && NT >= 1 && RPP >= 1 && IPW >= 1, "shape");

    __shared__ unsigned short ldsV[TR * H];  // prefetched V rows (raw bf16)
    __shared__ unsigned short hs[TR * HP];   // hidden tile, bf16
    __shared__ unsigned accs[16 * ACCSTR];   // per-slot running max (encoded)
    __shared__ signed char slotS[2][TR];

    int tid = threadIdx.x;
    int n0 = blockIdx.x * 16;

    int ln = tid & 15;
    int qd = (tid >> 4) & 3;
    int wv = tid >> 6;
    int rw = wv / CWAVES;
    int cw = wv % CWAVES;
    int lane = tid & 63;

    // ---- W2 fragments in registers, once ----
    short8 Bf[NT][KS];
#pragma unroll
    for (int nt = 0; nt < NT; nt++) {
        int col = cw * CPW + nt * 16 + ln;
#pragma unroll
        for (int ks = 0; ks < KS; ks++) {
            int kb = ks * 32 + qd * 8;
            short8 b;
#pragma unroll
            for (int j = 0; j < 8; j++)
                b[j] = (short)bfbits(W2[(size_t)(kb + j) * F + col]);
            Bf[nt][ks] = b;
        }
    }

    for (int idx = tid; idx < 16 * ACCSTR; idx += BLOCK) accs[idx] = ENC_NEG_INF;

    int e0 = rowptr[n0], e1 = rowptr[n0 + 16];

    // DMA lane mapping (constant per thread)
    int rofs = lane / CPR;                  // row within DMA instr
    int chk = lane % CPR;                   // 16B chunk within row

    // ---- prologue: indices + V prefetch for tile 0 ----
    if (e0 < e1) {
        if (tid < TR) {
            int p = e0 + tid;
            slotS[0][tid] = (p < e1) ? (signed char)(csr_dst[p] - n0) : -1;
        }
#pragma unroll
        for (int i = 0; i < IPW; i++) {
            int row0 = wv * RPW + i * RPI;
            int p = e0 + row0 + rofs;
            int src = (p < e1) ? csr_src[p] : 0;
            GLDS16(Vb + (size_t)src * H + chk * 8, ldsV + row0 * H);
        }
    }
    __syncthreads();   // drains DMA + slot writes

    int rid = tid / LPR;
    int kk = (tid % LPR) * 8;
    int cur = 0;

    for (int base = e0; base < e1; base += TR, cur ^= 1) {
        // ---- A: construct hidden tile from ldsV (+ U from L1) ----
#pragma unroll
        for (int r0 = 0; r0 < TR; r0 += RPP) {
            int r = r0 + rid;
            if (RPP >= TR || r < TR) {
                int sl = slotS[cur][r];
                uint4 w;
                if (sl >= 0) {
                    const float4 ua = *(const float4*)&U[(size_t)(n0 + sl) * H + kk];
                    const float4 ub = *(const float4*)&U[(size_t)(n0 + sl) * H + kk + 4];
                    const uint4 vv = *(const uint4*)&ldsV[r * H + kk];
                    w.x = pk2(fmaxf(ua.x + bflo(vv.x), 0.f), fmaxf(ua.y + bfhi(vv.x), 0.f));
                    w.y = pk2(fmaxf(ua.z + bflo(vv.y), 0.f), fmaxf(ua.w + bfhi(vv.y), 0.f));
                    w.z = pk2(fmaxf(ub.x + bflo(vv.z), 0.f), fmaxf(ub.y + bfhi(vv.z), 0.f));
                    w.w = pk2(fmaxf(ub.z + bflo(vv.w), 0.f), fmaxf(ub.w + bfhi(vv.w), 0.f));
                } else {
                    w = (uint4){0u, 0u, 0u, 0u};
                }
                *(uint4*)&hs[r * HP + kk] = w;
            }
        }
        __syncthreads();   // B1: hs ready; ldsV fully consumed

        // ---- B: issue next tile's indices + V DMA (in flight during MFMA) ----
        int nbase = base + TR;
        if (nbase < e1) {
            if (tid < TR) {
                int p = nbase + tid;
                slotS[cur ^ 1][tid] = (p < e1) ? (signed char)(csr_dst[p] - n0) : -1;
            }
#pragma unroll
            for (int i = 0; i < IPW; i++) {
                int row0 = wv * RPW + i * RPI;
                int p = nbase + row0 + rofs;
                int src = (p < e1) ? csr_src[p] : 0;
                GLDS16(Vb + (size_t)src * H + chk * 8, ldsV + row0 * H);
            }
        }

        // ---- C: MFMA ----
        f32x4 acc[2][NT];
#pragma unroll
        for (int mt = 0; mt < 2; mt++)
#pragma unroll
            for (int nt = 0; nt < NT; nt++)
                acc[mt][nt] = (f32x4){0.f, 0.f, 0.f, 0.f};

#pragma unroll
        for (int ks = 0; ks < KS; ks++) {
            int ko = ks * 32 + qd * 8;
            short8 a0 = *(const short8*)&hs[(rw * 32 + ln) * HP + ko];
            short8 a1 = *(const short8*)&hs[(rw * 32 + 16 + ln) * HP + ko];
#pragma unroll
            for (int nt = 0; nt < NT; nt++) {
                acc[0][nt] = __builtin_amdgcn_mfma_f32_16x16x32_bf16(a0, Bf[nt][ks], acc[0][nt], 0, 0, 0);
                acc[1][nt] = __builtin_amdgcn_mfma_f32_16x16x32_bf16(a1, Bf[nt][ks], acc[1][nt], 0, 0, 0);
            }
        }

        // ---- D: merge slot-runs in regs, then LDS atomicMax ----
#pragma unroll
        for (int mt = 0; mt < 2; mt++) {
            int rbase = rw * 32 + mt * 16 + qd * 4;
            char4 ss = *(const char4*)&slotS[cur][rbase];
#pragma unroll
            for (int nt = 0; nt < NT; nt++) {
                int colw = cw * CPW + nt * 16 + ln;
                float c0 = acc[mt][nt][0], c1 = acc[mt][nt][1];
                float c2 = acc[mt][nt][2], c3 = acc[mt][nt][3];
                float m3 = c3;
                float m2 = (ss.z == ss.w) ? fmaxf(c2, m3) : c2;
                float m1 = (ss.y == ss.z) ? fmaxf(c1, m2) : c1;
                float m0 = (ss.x == ss.y) ? fmaxf(c0, m1) : c0;
                if (ss.x >= 0)                 atomicMax(&accs[(int)ss.x * ACCSTR + colw], encf(m0));
                if (ss.y >= 0 && ss.y != ss.x) atomicMax(&accs[(int)ss.y * ACCSTR + colw], encf(m1));
                if (ss.z >= 0 && ss.z != ss.y) atomicMax(&accs[(int)ss.z * ACCSTR + colw], encf(m2));
                if (ss.w >= 0 && ss.w != ss.z) atomicMax(&accs[(int)ss.w * ACCSTR + colw], encf(m3));
            }
        }
        __syncthreads();   // B2: DMA drained; hs consumed; slots visible
    }

    for (int idx = tid; idx < 16 * F; idx += BLOCK) {
        int sl = idx / F, cc = idx % F;
        float m = decf(accs[sl * ACCSTR + cc]);
        float o = isfinite(m) ? (m + B2[cc]) : 0.f;   // empty segment -> 0
        storeY(&Y[(size_t)(n0 + sl) * F + cc], o);
    }
}

// ============================ global max-pool + FC ============================
__global__ void k_pool(const float* __restrict__ X3, const int* __restrict__ batch,
                       unsigned* poolEnc) {
    int gph = blockIdx.x;
    int seg = blockIdx.y;
    int c = threadIdx.x;
    int lo = 0, hi = NNODES;
    while (lo < hi) { int mid = (lo + hi) >> 1; if (batch[mid] < gph) lo = mid + 1; else hi = mid; }
    int start = lo;
    hi = NNODES;
    while (lo < hi) { int mid = (lo + hi) >> 1; if (batch[mid] < gph + 1) lo = mid + 1; else hi = mid; }
    int end = lo;
    int chunk = (end - start + 7) >> 3;
    int s = start + seg * chunk;
    int e = min(end, s + chunk);
    float m = -INFINITY;
    for (int n = s; n < e; n++) m = fmaxf(m, X3[(size_t)n * 256 + c]);
    atomicMax(&poolEnc[gph * 256 + c], encf(m));
}

__global__ __launch_bounds__(128) void k_fc(const unsigned* __restrict__ poolEnc,
                                            const float* __restrict__ Wfc,
                                            const float* __restrict__ Bfc,
                                            float* __restrict__ out) {
    __shared__ float p[256];
    int gph = blockIdx.x, c = threadIdx.x;
    for (int k = c; k < 256; k += 128) {
        float m = decf(poolEnc[gph * 256 + k]);
        p[k] = isfinite(m) ? m : 0.f;
    }
    __syncthreads();
    float s = Bfc[c];
    for (int k = 0; k < 256; k++) s += p[k] * Wfc[k * 128 + c];
    out[gph * 128 + c] = s;
}

// ============================ launch ============================
extern "C" void kernel_launch(void* const* d_in, const int* in_sizes, int n_in,
                              void* d_out, int out_size, void* d_ws, size_t ws_size,
                              hipStream_t stream) {
    const float* x     = (const float*)d_in[0];
    const int*   ei    = (const int*)d_in[1];
    const int*   batch = (const int*)d_in[2];
    const float* w1_1 = (const float*)d_in[3];
    const float* b1_1 = (const float*)d_in[4];
    const float* w2_1 = (const float*)d_in[5];
    const float* b2_1 = (const float*)d_in[6];
    const float* w1_2 = (const float*)d_in[7];
    const float* b1_2 = (const float*)d_in[8];
    const float* w2_2 = (const float*)d_in[9];
    const float* b2_2 = (const float*)d_in[10];
    const float* w1_3 = (const float*)d_in[11];
    const float* b1_3 = (const float*)d_in[12];
    const float* w2_3 = (const float*)d_in[13];
    const float* b2_3 = (const float*)d_in[14];
    const float* wfc  = (const float*)d_in[15];
    const float* bfc  = (const float*)d_in[16];
    float* out = (float*)d_out;

    char* ws = (char*)d_ws;
    size_t off = 0;
    auto alloc = [&](size_t bytes) {
        void* p = ws + off;
        off = (off + bytes + 255) & ~(size_t)255;
        return p;
    };
    int* deg      = (int*)alloc((size_t)NNODES * 4);
    int* cursor   = (int*)alloc((size_t)NNODES * 4);
    int* rowptr   = (int*)alloc((size_t)(NNODES + 1) * 4);
    int* bsum     = (int*)alloc(256 * 4);
    int* boff     = (int*)alloc(256 * 4);
    int* csr_src  = (int*)alloc((size_t)NEDGES * 4);
    int* csr_dst  = (int*)alloc((size_t)NEDGES * 4);
    float* U      = (float*)alloc((size_t)NNODES * 256 * 4);
    unsigned short* V = (unsigned short*)alloc((size_t)NNODES * 256 * 2);
    unsigned short* x1b = (unsigned short*)alloc((size_t)NNODES * 64 * 2);
    unsigned short* x2b = (unsigned short*)alloc((size_t)NNODES * 128 * 2);
    float* x3     = (float*)alloc((size_t)NNODES * 256 * 4);
    unsigned* poolEnc = (unsigned*)alloc((size_t)NGRAPHS * 256 * 4);
    (void)ws_size; (void)in_sizes; (void)n_in; (void)out_size;

    // CSR by dst (shared across the 3 layers)
    k_init<<<256, 256, 0, stream>>>(deg, cursor, poolEnc);
    k_count<<<NEDGES / 256, 256, 0, stream>>>(ei, deg);
    k_scan1<<<256, 256, 0, stream>>>(deg, rowptr, bsum);
    k_scan2<<<1, 256, 0, stream>>>(bsum, boff);
    k_scan3<<<256, 256, 0, stream>>>(rowptr, boff);
    k_scatter<<<NEDGES / 256, 256, 0, stream>>>(ei, rowptr, cursor, csr_src, csr_dst);

    // layer 1: FIN=3, H=64, F=64  (scalar uv; agg 2x2 waves, TR=64) -> x1 bf16
    k_uv<3, 64><<<NNODES / 16, 256, 0, stream>>>(x, w1_1, b1_1, U, V);
    k_agg<64, 64, 2, 2, unsigned short><<<NNODES / 16, 256, 0, stream>>>(U, V, w2_1, b2_1, rowptr, csr_src, csr_dst, x1b);
    // layer 2: K=64, H=128, F=128 (MFMA uv; agg 1x4 waves, TR=32) -> x2 bf16
    k_uvm<64, 128, 4><<<NNODES / 32, 256, 0, stream>>>(x1b, w1_2, b1_2, U, V);
    k_agg<128, 128, 1, 4, unsigned short><<<NNODES / 16, 256, 0, stream>>>(U, V, w2_2, b2_2, rowptr, csr_src, csr_dst, x2b);
    // layer 3: K=128, H=256, F=256 (MFMA uv; agg 1x8 waves, TR=32) -> x3 fp32
    k_uvm<128, 256, 8><<<NNODES / 32, 512, 0, stream>>>(x2b, w1_3, b1_3, U, V);
    k_agg<256, 256, 1, 8, float><<<NNODES / 16, 512, 0, stream>>>(U, V, w2_3, b2_3, rowptr, csr_src, csr_dst, x3);

    // global max pool + FC
    k_pool<<<dim3(NGRAPHS, 8), 256, 0, stream>>>(x3, batch, poolEnc);
    k_fc<<<NGRAPHS, 128, 0, stream>>>(poolEnc, wfc, bfc, out);
}